// Round 1
// baseline (217.377 us; speedup 1.0000x reference)
//
#include <hip/hip_runtime.h>

// ColorQuantizer: out[b,c,h,w] = palette[argmin_i dist(processed(x[b,:,h,w]), palette_i)][c]
// processed = relu(x@W1 + b1) @ W2 + b2   (all fp32, replicate reference op order)
//
// This revision: (1) argmin in the sq domain (sqrt is monotone) with an exact
// second-min screen + rare sqrtf fixup path, removing all 16 IEEE sqrt
// expansions from the hot path; (2) rolled loops with packed float4 LDS
// broadcasts to shrink code from ~48KB (I$ thrash) to ~5KB.

#define PV(v) ((float)(v)/255.0f*2.0f-1.0f)
#define ROWF(r,g,c) {PV(r), PV(g), PV(c)}

// Runtime-indexed palette table (global .rodata) for the final gather.
__device__ const float PALG[16][3] = {
  ROWF(0,0,0),       ROWF(255,255,255), ROWF(255,0,0),     ROWF(0,255,0),
  ROWF(0,0,255),     ROWF(255,255,0),   ROWF(255,0,255),   ROWF(0,255,255),
  ROWF(128,128,128), ROWF(128,0,0),     ROWF(0,128,0),     ROWF(0,0,128),
  ROWF(128,128,0),   ROWF(128,0,128),   ROWF(0,128,128),   ROWF(192,192,192)
};

constexpr int COLI[16][3] = {
  {0,0,0},{255,255,255},{255,0,0},{0,255,0},{0,0,255},{255,255,0},
  {255,0,255},{0,255,255},{128,128,128},{128,0,0},{0,128,0},{0,0,128},
  {128,128,0},{128,0,128},{0,128,128},{192,192,192}
};
constexpr float PVF(int v){ return (float)v/255.0f*2.0f-1.0f; }
constexpr float PXc(int i){ return PVF(COLI[i][0]); }
constexpr float PYc(int i){ return PVF(COLI[i][1]); }
constexpr float PZc(int i){ return PVF(COLI[i][2]); }
// sum(PALETTE*PALETTE, axis=-1) with the reference's reduce order: (x*x + y*y) + z*z
constexpr float PSQc(int i){ return (PXc(i)*PXc(i) + PYc(i)*PYc(i)) + PZc(i)*PZc(i); }

// {px, py, pz, psq} per palette entry, +1 dummy slot for prefetch overrun.
#define PE(i) {PXc(i), PYc(i), PZc(i), PSQc(i)}
__device__ const float PAL4f[17][4] = {
  PE(0),PE(1),PE(2),PE(3),PE(4),PE(5),PE(6),PE(7),
  PE(8),PE(9),PE(10),PE(11),PE(12),PE(13),PE(14),PE(15),
  {0.0f,0.0f,0.0f,0.0f}
};

constexpr int HW    = 512*512;   // per-channel plane
constexpr int PXT   = 8;         // pixels per thread (2x float4)
constexpr int BLOCK = 256;

// Rare path: bit-exact replay of the reference distance loop (correctly-rounded
// sqrtf, first-occurrence argmin over d). Only taken when the second-min screen
// says sqrt rounding could collide (expected: a handful of pixels per launch).
__device__ __attribute__((noinline)) int argmin_exact(float p0, float p1, float p2, float psq)
{
#pragma clang fp contract(off)
    float bd = 3.4e38f;
    int   bi = 0;
#pragma unroll 1
    for (int i = 0; i < 16; ++i) {
        const float px = PAL4f[i][0], py = PAL4f[i][1], pz = PAL4f[i][2], pq = PAL4f[i][3];
        float dot = __builtin_fmaf(p2, pz, __builtin_fmaf(p1, py, p0*px));
        float sq  = (psq - 2.0f*dot) + pq;
        float d   = sqrtf(fmaxf(sq, 0.0f));
        if (d < bd) { bd = d; bi = i; }
    }
    return bi;
}

__global__ __launch_bounds__(BLOCK) void cq_kernel(
    const float* __restrict__ x,  const float* __restrict__ W1g,
    const float* __restrict__ b1g, const float* __restrict__ W2g,
    const float* __restrict__ b2g, float* __restrict__ out)
{
#pragma clang fp contract(off)
    // Packed weight layout for 1x ds_read_b128 per table per j:
    //   sWA[j] = {W1[0][j], W1[1][j], W1[2][j], b1[j]}
    //   sWB[j] = {W2[j][0], W2[j][1], W2[j][2], 0}
    // +1 dummy slot each for the prefetch overrun at j=31 / i=15.
    __shared__ float4 sWA[33];
    __shared__ float4 sWB[33];
    __shared__ float4 sPAL[17];
    __shared__ float4 sB2s;

    const int t = threadIdx.x;
    if (t < 32) {
        sWA[t] = make_float4(W1g[t], W1g[32+t], W1g[64+t], b1g[t]);
    } else if (t < 64) {
        const int j = t - 32;
        sWB[j] = make_float4(W2g[3*j], W2g[3*j+1], W2g[3*j+2], 0.0f);
    } else if (t < 81) {
        const int i = t - 64;
        sPAL[i] = make_float4(PAL4f[i][0], PAL4f[i][1], PAL4f[i][2], PAL4f[i][3]);
    } else if (t == 81) {
        sB2s = make_float4(b2g[0], b2g[1], b2g[2], 0.0f);
    } else if (t == 82) {
        sWA[32] = make_float4(0.0f, 0.0f, 0.0f, 0.0f);
        sWB[32] = make_float4(0.0f, 0.0f, 0.0f, 0.0f);
    }
    __syncthreads();

    const int pix = (blockIdx.x * BLOCK + t) * PXT;   // < 2^23, int is fine
    const int img = pix >> 18;                        // HW = 2^18
    const int hw  = pix & (HW - 1);
    const size_t base = (size_t)img * (size_t)(3*HW) + (size_t)hw;

    float X0[PXT], X1[PXT], X2[PXT];
    {
        float4 a0 = *(const float4*)(x + base);
        float4 a1 = *(const float4*)(x + base + 4);
        float4 c0 = *(const float4*)(x + base + HW);
        float4 c1 = *(const float4*)(x + base + HW + 4);
        float4 e0 = *(const float4*)(x + base + 2*HW);
        float4 e1 = *(const float4*)(x + base + 2*HW + 4);
        X0[0]=a0.x; X0[1]=a0.y; X0[2]=a0.z; X0[3]=a0.w;
        X0[4]=a1.x; X0[5]=a1.y; X0[6]=a1.z; X0[7]=a1.w;
        X1[0]=c0.x; X1[1]=c0.y; X1[2]=c0.z; X1[3]=c0.w;
        X1[4]=c1.x; X1[5]=c1.y; X1[6]=c1.z; X1[7]=c1.w;
        X2[0]=e0.x; X2[1]=e0.y; X2[2]=e0.z; X2[3]=e0.w;
        X2[4]=e1.x; X2[5]=e1.y; X2[6]=e1.z; X2[7]=e1.w;
    }

    // processed accumulators; dot runs from 0 so fma(h,u,0) == h*u exactly
    float P0[PXT], P1[PXT], P2[PXT];
#pragma unroll
    for (int k = 0; k < PXT; ++k) { P0[k]=0.0f; P1[k]=0.0f; P2[k]=0.0f; }

    // Fused MLP, rolled over j (x2) with +1 LDS prefetch:
    // hidden_j = relu((x0*w0 fma x1*w1 fma x2*w2) + b1_j); P_c += h*W2[j][c]
    {
        float4 wa = sWA[0];
        float4 wb = sWB[0];
#pragma unroll 2
        for (int j = 0; j < 32; ++j) {
            const float4 wa_n = sWA[j+1];
            const float4 wb_n = sWB[j+1];
#pragma unroll
            for (int k = 0; k < PXT; ++k) {
                float h = __builtin_fmaf(X2[k], wa.z, __builtin_fmaf(X1[k], wa.y, X0[k]*wa.x));
                h = h + wa.w;
                h = fmaxf(h, 0.0f);
                P0[k] = __builtin_fmaf(h, wb.x, P0[k]);
                P1[k] = __builtin_fmaf(h, wb.y, P1[k]);
                P2[k] = __builtin_fmaf(h, wb.z, P2[k]);
            }
            wa = wa_n; wb = wb_n;
        }
    }

    // Distance phase in the sq domain. Track min (m1, first index bi) and
    // second-min value (m2) of the clamped squared distances, computed with
    // the reference's exact op order/rounding.
    float p0a[PXT], p1a[PXT], p2a[PXT], psqa[PXT];
    float m1[PXT], m2[PXT];
    int   bi[PXT];
    {
        const float4 b2v = sB2s;
#pragma unroll
        for (int k = 0; k < PXT; ++k) {
            const float p0 = P0[k] + b2v.x;
            const float p1 = P1[k] + b2v.y;
            const float p2 = P2[k] + b2v.z;
            p0a[k] = p0; p1a[k] = p1; p2a[k] = p2;
            psqa[k] = (p0*p0 + p1*p1) + p2*p2;  // reference reduce order
            m1[k] = 3.4e38f; m2[k] = 3.4e38f; bi[k] = 0;
        }

        float4 pc = sPAL[0];
#pragma unroll 2
        for (int i = 0; i < 16; ++i) {
            const float4 pn = sPAL[i+1];
#pragma unroll
            for (int k = 0; k < PXT; ++k) {
                float dot = __builtin_fmaf(p2a[k], pc.z, __builtin_fmaf(p1a[k], pc.y, p0a[k]*pc.x));
                float sq  = (psqa[k] - 2.0f*dot) + pc.w;   // (psq - 2*dot) + palsq
                sq = fmaxf(sq, 0.0f);
                const bool lt = sq < m1[k];
                m2[k] = fminf(m2[k], fmaxf(sq, m1[k]));    // uses OLD m1
                m1[k] = fminf(m1[k], sq);
                bi[k] = lt ? i : bi[k];                    // first-occurrence argmin
            }
            pc = pn;
        }
    }

    // Exactness screen: if the second-min is within 1e-6 relative of the min,
    // correctly-rounded sqrt could map both to the same d — replay the
    // reference loop for that pixel. (Provably safe: rel gap > 2^-20 implies
    // distinct rounded sqrts; also catches exact ties and the 0/0 case.)
#pragma unroll
    for (int k = 0; k < PXT; ++k) {
        if (__builtin_expect(m2[k] - m1[k] <= 1e-6f * m1[k], 0)) {
            bi[k] = argmin_exact(p0a[k], p1a[k], p2a[k], psqa[k]);
        }
    }

    float* op = out + base;   // output has the same [b][c][hw] layout
    float4 o;
    o = make_float4(PALG[bi[0]][0], PALG[bi[1]][0], PALG[bi[2]][0], PALG[bi[3]][0]);
    *(float4*)(op) = o;
    o = make_float4(PALG[bi[4]][0], PALG[bi[5]][0], PALG[bi[6]][0], PALG[bi[7]][0]);
    *(float4*)(op + 4) = o;
    o = make_float4(PALG[bi[0]][1], PALG[bi[1]][1], PALG[bi[2]][1], PALG[bi[3]][1]);
    *(float4*)(op + HW) = o;
    o = make_float4(PALG[bi[4]][1], PALG[bi[5]][1], PALG[bi[6]][1], PALG[bi[7]][1]);
    *(float4*)(op + HW + 4) = o;
    o = make_float4(PALG[bi[0]][2], PALG[bi[1]][2], PALG[bi[2]][2], PALG[bi[3]][2]);
    *(float4*)(op + 2*HW) = o;
    o = make_float4(PALG[bi[4]][2], PALG[bi[5]][2], PALG[bi[6]][2], PALG[bi[7]][2]);
    *(float4*)(op + 2*HW + 4) = o;
}

extern "C" void kernel_launch(void* const* d_in, const int* in_sizes, int n_in,
                              void* d_out, int out_size, void* d_ws, size_t ws_size,
                              hipStream_t stream) {
    const float* x  = (const float*)d_in[0];
    const float* W1 = (const float*)d_in[1];
    const float* b1 = (const float*)d_in[2];
    const float* W2 = (const float*)d_in[3];
    const float* b2 = (const float*)d_in[4];
    float* outp = (float*)d_out;

    constexpr int NPIX = 32 * HW;                    // 8,388,608
    constexpr int GRID = NPIX / (BLOCK * PXT);       // 4096 blocks, exact
    hipLaunchKernelGGL(cq_kernel, dim3(GRID), dim3(BLOCK), 0, stream,
                       x, W1, b1, W2, b2, outp);
}